// Round 3
// baseline (412.408 us; speedup 1.0000x reference)
//
#include <hip/hip_runtime.h>

// MaxoutDynamic: per row of [B, 4096] fp32, zero the 2048 smallest values,
// scale the 2048 survivors by 4096/2048 = 2.0.
//
// v4: v3 (block-per-row, narrow-band exact selection) with the selection
// phases de-serialized:
//  - scan and candidate-rank are computed REDUNDANTLY BY ALL 4 WAVES
//    (each wave reads the same 1 KiB histogram / candidate list and derives
//    identical selbin/rank/tau in registers via shuffles). No LDS broadcast
//    of scan results, no wave0-only phases with 3 waves parked at a barrier.
//  - fine path: 3 block barriers (was 5). Each __syncthreads on gfx950
//    drains vmcnt(0)+lgkmcnt(0), so fewer barriers = fewer forced drains.
//  - __launch_bounds__(256, 8): cap VGPRs at 64 -> 8 blocks/CU (max
//    occupancy for 256-thread blocks); data is 16 VGPRs/thread, ~50 live.
//  - Exact rank-2048 selection, identical tie semantics to v1/v3:
//      nlo = #(x < -0.125); 256-bin fine histogram over [-0.125, 0.125)
//      (sample median of 4096 N(0,1) is 0 +/- ~0.02 -> in-band except at
//      ~6.4 sigma, P ~ 8e-11/row; ~10% of elements touch LDS atomics);
//      conflict-free uint4 scan -> bin + rank-in-bin; gather bin's ~2
//      candidates; all-pairs rank -> exact tau. Block-uniform wide-range
//      fallback keeps correctness for ANY data.
//  - out = (v >= tau) ? 2v : 0; nontemporal loads/stores (pure streaming).

#define FEAT   4096
#define NDROP  2048
#define TPB    256
#define NBIN   256        // == TPB (zeroing assumes this)
#define CAP    256        // candidate list capacity (fine path expects ~2)

typedef float f32x4 __attribute__((ext_vector_type(4)));

// Wave-wide scan of 256 bins (4/lane, conflict-free b128 read): find the bin
// containing rank rel and the rank within it. All lanes return the same
// result. Returns false iff rel is outside the histogrammed population.
__device__ __forceinline__ bool scan_pick(const unsigned int* __restrict__ hist,
                                          int lane, int rel,
                                          unsigned int& selbin, unsigned int& rrout) {
    const uint4 c4 = ((const uint4*)hist)[lane];
    const unsigned int csum = c4.x + c4.y + c4.z + c4.w;
    unsigned int incl = csum;
#pragma unroll
    for (int d = 1; d < 64; d <<= 1) {
        unsigned int y = __shfl_up(incl, d, 64);
        if (lane >= d) incl += y;
    }
    const unsigned int excl = incl - csum;
    const bool has = (rel >= 0) && ((unsigned)rel >= excl) &&
                     ((unsigned)rel < excl + csum);
    const unsigned long long bal = __ballot(has);
    if (bal == 0ull) return false;
    const int src = (int)(__ffsll(bal) - 1);
    int pack = 0;
    if (has) {
        unsigned int rr = (unsigned)rel - excl;
        int bsel;
        if (rr < c4.x) { bsel = 0; }
        else {
            rr -= c4.x;
            if (rr < c4.y) { bsel = 1; }
            else {
                rr -= c4.y;
                if (rr < c4.z) { bsel = 2; }
                else { rr -= c4.z; bsel = 3; }
            }
        }
        pack = ((lane * 4 + bsel) << 16) | (int)rr;
    }
    pack = __shfl(pack, src, 64);
    selbin = (unsigned)(pack >> 16);
    rrout  = (unsigned)(pack & 0xffff);
    return true;
}

// Wave-wide all-pairs rank among n candidates in LDS -> value of rank rr.
// All lanes return the same tau.
__device__ __forceinline__ float rank_tau(const float* __restrict__ list,
                                          int n, unsigned int rr, int lane) {
    float tauv = 0.0f;
    bool  got  = false;
    for (int c0 = lane; c0 < n; c0 += 64) {
        const float vc = list[c0];
        unsigned int r = 0u, mm = 0u;
        for (int j = 0; j < n; ++j) {
            const float vj = list[j];          // same addr all lanes -> broadcast
            r  += (vj <  vc) ? 1u : 0u;
            mm += (vj == vc) ? 1u : 0u;
        }
        if (r <= rr && rr < r + mm) { tauv = vc; got = true; }  // ties: same bits
    }
    const unsigned long long gm = __ballot(got);
    const int s2 = gm ? (int)(__ffsll(gm) - 1) : 0;
    return __shfl(tauv, s2, 64);
}

__global__ __launch_bounds__(TPB, 8)
void MaxoutDynamic_55181739819231_kernel(const float* __restrict__ in,
                                         float* __restrict__ out) {
    const int row  = blockIdx.x;
    const int t    = threadIdx.x;
    const int lane = t & 63;

    const f32x4* inrow  = (const f32x4*)(in  + (size_t)row * FEAT);
    f32x4*       outrow = (f32x4*)      (out + (size_t)row * FEAT);

    __shared__ __align__(16) unsigned int hist[NBIN];
    __shared__ float        list[CAP];
    __shared__ unsigned int s_cnt;
    __shared__ unsigned int s_nlo;

    // ---- load row: thread t owns float4 indices {t, t+256, t+512, t+768} ----
    f32x4 xs[4];
#pragma unroll
    for (int j = 0; j < 4; ++j)
        xs[j] = __builtin_nontemporal_load(&inrow[t + j * TPB]);

    // ---- zero histogram / scalars (NBIN == TPB: one store per thread) ----
    hist[t] = 0u;
    if (t == 0) { s_cnt = 0u; s_nlo = 0u; }
    __syncthreads();                                   // barrier 1

    // ---- pass 1: nlo count + fine histogram of [-0.125, 0.125) ----
    const float LO = -0.125f, HI = 0.125f;
    int nlo = 0;
#pragma unroll
    for (int j = 0; j < 4; ++j) {
#pragma unroll
        for (int k = 0; k < 4; ++k) {
            const float x = xs[j][k];
            nlo += (x < LO) ? 1 : 0;
            if (x >= LO && x < HI) {
                int b = (int)((x - LO) * 1024.0f);     // 256 bins over width 0.25
                b = b > (NBIN - 1) ? (NBIN - 1) : b;   // fp edge safety
                atomicAdd(&hist[b], 1u);
            }
        }
    }
#pragma unroll
    for (int d = 1; d < 64; d <<= 1) nlo += __shfl_xor(nlo, d, 64);
    if (lane == 0) atomicAdd(&s_nlo, (unsigned)nlo);
    __syncthreads();                                   // barrier 2

    // ---- scan: ALL waves compute identical selbin/rr (no LDS broadcast) ----
    unsigned int selbin, rr;
    const bool found = scan_pick(hist, lane, NDROP - (int)s_nlo, selbin, rr);
    // 'found' is block-uniform: every wave reads the same hist and s_nlo.

    if (found) {
        // ---- gather the selected fine bin's candidates ----
#pragma unroll
        for (int j = 0; j < 4; ++j) {
#pragma unroll
            for (int k = 0; k < 4; ++k) {
                const float x = xs[j][k];
                if (x >= LO && x < HI) {
                    int b = (int)((x - LO) * 1024.0f);
                    b = b > (NBIN - 1) ? (NBIN - 1) : b;
                    if ((unsigned)b == selbin) {
                        unsigned int idx = atomicAdd(&s_cnt, 1u);
                        if (idx < CAP) list[idx] = x;
                    }
                }
            }
        }
        __syncthreads();                               // barrier 3
    } else {
        // ---- fallback: wide 256-bin histogram over [-4,4), clamped tails ----
        // (block-uniform branch; effectively never taken for N(0,1) data)
        __syncthreads();             // all waves done reading fine hist
        hist[t] = 0u;
        __syncthreads();
#pragma unroll
        for (int j = 0; j < 4; ++j) {
#pragma unroll
            for (int k = 0; k < 4; ++k) {
                int b = (int)((xs[j][k] + 4.0f) * 32.0f);
                b = b < 0 ? 0 : (b > (NBIN - 1) ? (NBIN - 1) : b);
                atomicAdd(&hist[b], 1u);
            }
        }
        __syncthreads();
        scan_pick(hist, lane, NDROP, selbin, rr);  // total 4096 > NDROP: found
#pragma unroll
        for (int j = 0; j < 4; ++j) {
#pragma unroll
            for (int k = 0; k < 4; ++k) {
                const float x = xs[j][k];
                int b = (int)((x + 4.0f) * 32.0f);
                b = b < 0 ? 0 : (b > (NBIN - 1) ? (NBIN - 1) : b);
                if ((unsigned)b == selbin) {
                    unsigned int idx = atomicAdd(&s_cnt, 1u);
                    if (idx < CAP) list[idx] = x;
                }
            }
        }
        __syncthreads();
    }

    // ---- rank: ALL waves compute identical tau (no LDS broadcast) ----
    int n = (int)s_cnt; if (n > CAP) n = CAP;
    const float tau = rank_tau(list, n, rr, lane);

    // ---- write: keep (x2) if v >= tau, else 0; nontemporal stores ----
#pragma unroll
    for (int j = 0; j < 4; ++j) {
        f32x4 o;
#pragma unroll
        for (int k = 0; k < 4; ++k)
            o[k] = (xs[j][k] >= tau) ? 2.0f * xs[j][k] : 0.0f;
        __builtin_nontemporal_store(o, &outrow[t + j * TPB]);
    }
}

extern "C" void kernel_launch(void* const* d_in, const int* in_sizes, int n_in,
                              void* d_out, int out_size, void* d_ws, size_t ws_size,
                              hipStream_t stream) {
    const float* feat = (const float*)d_in[0];
    float* out = (float*)d_out;
    const int rows = in_sizes[0] / FEAT;   // 16384
    MaxoutDynamic_55181739819231_kernel<<<rows, TPB, 0, stream>>>(feat, out);
}